// Round 1
// baseline (4149.828 us; speedup 1.0000x reference)
//
#include <hip/hip_runtime.h>
#include <cstdint>
#include <cstddef>

// ---------------------------------------------------------------------------
// Trainer_91216515433187: BN + Dense + LSTM encoder (1024 steps) + 35-step
// autoregressive LSTM decoder.
//
// Design (round 1):
//  * Precompute: fold BN+W_pulse+lstm_k into Weff(8x1024)+zbias; W_eis@lstm_k
//    into Deff(2x1024)+dbias; transpose lstm_rk -> rkT[col][k] f16 so MFMA
//    B-fragments are contiguous 16B loads.
//  * Main: 32 wgs x 512 thr. wg (tile = bid&15, half = bid>>4) owns batch rows
//    tile*16..+16 and hidden cols half*128..+128 (all 4 gates). Recurrent
//    weights are register-resident f16 B-frags (128 VGPR/thread). Each step:
//    z = h@rk (MFMA 16x16x32 f16, fp32 acc) + pulse@Weff + bias, gates in
//    fp32, h halves exchanged via parity-double-buffered global buffer with
//    one agent-scope release-add/acquire-spin per tile per step.
//    Pairs are (bid, bid+16) so both land on the same XCD under %8 round-robin
//    (performance heuristic only; fences give correctness regardless).
// ---------------------------------------------------------------------------

typedef _Float16 h8 __attribute__((ext_vector_type(8)));
typedef float f4 __attribute__((ext_vector_type(4)));

// ws byte offsets
#define WS_CTR    0         // 16 x int
#define WS_HBUF   256       // 2 par x 16 tiles x 16 rows x 256 k, f16 = 262144 B
#define WS_RKT    262400    // 1024 cols x 256 k f16 = 524288 B
#define WS_WEFF   786688    // 1024 cols x 8 f f16 = 16384 B
#define WS_WMLP   803072    // 2 e x 256 k f16 = 1024 B
#define WS_DEFF   804096    // 2 x 1024 f32 = 8192 B
#define WS_ZB     812288    // 1024 f32
#define WS_DB     816384    // 1024 f32
#define WS_TOTAL  820480

__device__ __forceinline__ float fexp2(float x){
#if __has_builtin(__builtin_amdgcn_exp2f)
  return __builtin_amdgcn_exp2f(x);
#else
  return exp2f(x);
#endif
}
__device__ __forceinline__ float frcp(float x){
#if __has_builtin(__builtin_amdgcn_rcpf)
  return __builtin_amdgcn_rcpf(x);
#else
  return 1.f / x;
#endif
}
__device__ __forceinline__ float sigf(float x){
  return frcp(1.f + fexp2(-1.44269504f * x));
}
__device__ __forceinline__ float tanh_f(float x){
  // tanh(x) = 2*sigmoid(2x) - 1
  return 2.f * frcp(1.f + fexp2(-2.88539008f * x)) - 1.f;
}

__global__ void zero_ws_k(uint32_t* __restrict__ p, int n){
  int i = blockIdx.x * 256 + threadIdx.x;
  if (i < n) p[i] = 0u;
}

// grid 1024 x 256 threads
__global__ void precompute_k(const float* __restrict__ bn_gamma,
                             const float* __restrict__ bn_beta,
                             const float* __restrict__ bn_mean,
                             const float* __restrict__ bn_var,
                             const float* __restrict__ W_pulse,   // (8,256)
                             const float* __restrict__ b_pulse,   // (256)
                             const float* __restrict__ lstm_k,    // (256,1024)
                             const float* __restrict__ lstm_rk,   // (256,1024)
                             const float* __restrict__ lstm_b,    // (1024)
                             const float* __restrict__ W_eis,     // (2,256)
                             const float* __restrict__ b_eis,     // (256)
                             const float* __restrict__ W_mlp,     // (256,2)
                             _Float16* __restrict__ rkT,          // [col][k]
                             _Float16* __restrict__ WeffT,        // [col][f]
                             _Float16* __restrict__ WmlpT,        // [e][k]
                             float* __restrict__ Deff,            // [e][col]
                             float* __restrict__ zbias,
                             float* __restrict__ dbias)
{
  int gid = blockIdx.x * 256 + threadIdx.x;   // 0..262143
  // (a) rkT transpose + cvt
  {
    int col = gid >> 8;
    int k   = gid & 255;
    rkT[col * 256 + k] = (_Float16)lstm_rk[k * 1024 + col];
  }
  // (c) WmlpT
  if (gid < 512) {
    int e = gid >> 8, k = gid & 255;
    WmlpT[e * 256 + k] = (_Float16)W_mlp[k * 2 + e];
  }
  // (b) per output-column folded weights
  if (gid < 1024) {
    int j = gid;
    float a[8], bv[8];
#pragma unroll
    for (int f = 0; f < 8; ++f) {
      float af = bn_gamma[f] * rsqrtf(bn_var[f] + 1e-3f);
      a[f]  = af;
      bv[f] = bn_beta[f] - bn_mean[f] * af;
    }
    float m[8] = {0,0,0,0,0,0,0,0};
    float d0 = 0.f, d1 = 0.f, zb2 = 0.f, db2 = 0.f;
    for (int k = 0; k < 256; ++k) {
      float lk = lstm_k[k * 1024 + j];
#pragma unroll
      for (int f = 0; f < 8; ++f) m[f] += W_pulse[f * 256 + k] * lk;
      d0  += W_eis[k]       * lk;
      d1  += W_eis[256 + k] * lk;
      zb2 += b_pulse[k] * lk;
      db2 += b_eis[k]   * lk;
    }
    float zb = lstm_b[j] + zb2;
#pragma unroll
    for (int f = 0; f < 8; ++f) {
      zb += bv[f] * m[f];
      WeffT[j * 8 + f] = (_Float16)(a[f] * m[f]);
    }
    zbias[j] = zb;
    dbias[j] = lstm_b[j] + db2;
    Deff[j]        = d0;
    Deff[1024 + j] = d1;
  }
}

// 32 blocks x 512 threads
__global__ __launch_bounds__(512, 2)
void lstm_main_k(const float* __restrict__ pulse,      // (256,1024,8)
                 const float* __restrict__ embed,      // (1,2)
                 const float* __restrict__ b_mlp,      // (2)
                 const float* __restrict__ scale_w,    // (2)
                 const float* __restrict__ scale_b,    // (2)
                 const _Float16* __restrict__ rkT,
                 const _Float16* __restrict__ WeffT,
                 const _Float16* __restrict__ WmlpT,
                 const float* __restrict__ Deff,
                 const float* __restrict__ zbias,
                 const float* __restrict__ dbias,
                 _Float16* __restrict__ hbuf,          // [par][tile][row][k]
                 int* __restrict__ ctr,                // [16]
                 float* __restrict__ out)              // (256,35,2)
{
  const int tid  = threadIdx.x;
  const int wave = tid >> 6;
  const int lane = tid & 63;
  const int quad = lane >> 4;
  const int n    = lane & 15;

  const int bid     = blockIdx.x;
  const int tile    = bid & 15;
  const int half_id = bid >> 4;
  const int b0      = tile * 16;
  const int hc0     = half_id * 128 + wave * 16;  // wave's hidden col base
  const int col_h   = hc0 + n;                    // this lane's hidden col

  __shared__ _Float16 wm_lds[8 * 64 * 8];  // W_mlp B-frags: [s8][lane][8]
  __shared__ float    tok_lds[32];         // [row][e]

  // Build W_mlp fragment LDS (N padded 2->16 with zeros).
  {
    int s8 = tid >> 6, L = tid & 63;
    int nn = L & 15, kq = L >> 4;
    h8 v;
#pragma unroll
    for (int j = 0; j < 8; ++j) {
      int k = s8 * 32 + kq * 8 + j;
      v[j] = (nn < 2) ? WmlpT[nn * 256 + k] : (_Float16)0.f;
    }
    *reinterpret_cast<h8*>(&wm_lds[(s8 * 64 + L) * 8]) = v;
  }

  // Register-resident weight fragments.
  h8 W[4][8];      // recurrent: gate g, k-step s8
  h8 Wf[4];        // pulse Weff (K padded 8->32)
  float zb[4], db[4], D0[4], D1[4];
#pragma unroll
  for (int g = 0; g < 4; ++g) {
    int col = g * 256 + col_h;
    const _Float16* wp = rkT + col * 256 + quad * 8;
#pragma unroll
    for (int s8 = 0; s8 < 8; ++s8)
      W[g][s8] = *reinterpret_cast<const h8*>(wp + s8 * 32);
    if (quad == 0) {
      Wf[g] = *reinterpret_cast<const h8*>(WeffT + col * 8);
    } else {
#pragma unroll
      for (int j = 0; j < 8; ++j) Wf[g][j] = (_Float16)0.f;
    }
    zb[g] = zbias[col];
    db[g] = dbias[col];
    D0[g] = Deff[col];
    D1[g] = Deff[1024 + col];
  }
  const float sw  = (n < 2) ? scale_w[n] : 0.f;
  const float sb_ = (n < 2) ? scale_b[n] : 0.f;
  const float bm  = (n < 2) ? b_mlp[n]   : 0.f;

  f4 c_frag = {0.f, 0.f, 0.f, 0.f};

  __syncthreads();

  const int hrow_rd = (tile * 16 + n) * 256 + quad * 8;          // A-frag base (row=n)
  const int hrow_wr = (tile * 16 + quad * 4) * 256 + col_h;      // store base (row=quad*4+r)
  const float* prow = pulse + (size_t)(b0 + n) * 1024 * 8;       // quad==0 lanes only

  // ---------------- encoder: t = 0..1023 ----------------
  for (int t = 0; t < 1024; ++t) {
    const int parR = t & 1;
    const int parW = parR ^ 1;

    const _Float16* hb = hbuf + parR * 65536 + hrow_rd;
    h8 ha[8];
#pragma unroll
    for (int s8 = 0; s8 < 8; ++s8)
      ha[s8] = *reinterpret_cast<const h8*>(hb + s8 * 32);

    h8 pa;
#pragma unroll
    for (int j = 0; j < 8; ++j) pa[j] = (_Float16)0.f;
    if (quad == 0) {
      const f4* pp = reinterpret_cast<const f4*>(prow + (size_t)t * 8);
      f4 p0 = pp[0], p1 = pp[1];
      pa[0] = (_Float16)p0[0]; pa[1] = (_Float16)p0[1];
      pa[2] = (_Float16)p0[2]; pa[3] = (_Float16)p0[3];
      pa[4] = (_Float16)p1[0]; pa[5] = (_Float16)p1[1];
      pa[6] = (_Float16)p1[2]; pa[7] = (_Float16)p1[3];
    }

    f4 acc[4];
#pragma unroll
    for (int g = 0; g < 4; ++g) {
      acc[g][0] = zb[g]; acc[g][1] = zb[g]; acc[g][2] = zb[g]; acc[g][3] = zb[g];
      acc[g] = __builtin_amdgcn_mfma_f32_16x16x32_f16(pa, Wf[g], acc[g], 0, 0, 0);
    }
#pragma unroll
    for (int s8 = 0; s8 < 8; ++s8) {
#pragma unroll
      for (int g = 0; g < 4; ++g)
        acc[g] = __builtin_amdgcn_mfma_f32_16x16x32_f16(ha[s8], W[g][s8], acc[g], 0, 0, 0);
    }

    _Float16* hw = hbuf + parW * 65536 + hrow_wr;
#pragma unroll
    for (int r = 0; r < 4; ++r) {
      float iv = sigf(acc[0][r]);
      float fv = sigf(acc[1][r]);
      float gv = tanh_f(acc[2][r]);
      float ov = sigf(acc[3][r]);
      float cc = fv * c_frag[r] + iv * gv;
      c_frag[r] = cc;
      hw[r * 256] = (_Float16)(ov * tanh_f(cc));
    }

    __syncthreads();
    if (tid == 0) {
      __hip_atomic_fetch_add(ctr + tile, 1, __ATOMIC_RELEASE, __HIP_MEMORY_SCOPE_AGENT);
      while (__hip_atomic_load(ctr + tile, __ATOMIC_ACQUIRE, __HIP_MEMORY_SCOPE_AGENT)
             < 2 * (t + 1)) { }
    }
    __syncthreads();
  }

  // ---------------- decoder: 35 steps ----------------
  if (tid < 32) tok_lds[tid] = embed[tid & 1];
  __syncthreads();

  for (int s = 0; s < 35; ++s) {
    const int t = 1024 + s;
    const int parR = t & 1;
    const int parW = parR ^ 1;

    const _Float16* hb = hbuf + parR * 65536 + hrow_rd;
    h8 ha[8];
#pragma unroll
    for (int s8 = 0; s8 < 8; ++s8)
      ha[s8] = *reinterpret_cast<const h8*>(hb + s8 * 32);

    if (s > 0) {
      // pred_{s-1} = h_t @ W_mlp + b_mlp  (redundant across waves; wave0 publishes)
      f4 pf; pf[0] = bm; pf[1] = bm; pf[2] = bm; pf[3] = bm;
#pragma unroll
      for (int s8 = 0; s8 < 8; ++s8) {
        h8 wb = *reinterpret_cast<const h8*>(&wm_lds[(s8 * 64 + lane) * 8]);
        pf = __builtin_amdgcn_mfma_f32_16x16x32_f16(ha[s8], wb, pf, 0, 0, 0);
      }
      if (wave == 0 && n < 2) {
#pragma unroll
        for (int r = 0; r < 4; ++r) {
          int row = quad * 4 + r;
          float v = pf[r];
          tok_lds[row * 2 + n] = v;
          if (half_id == 0)
            out[((b0 + row) * 35 + (s - 1)) * 2 + n] = v * sw + sb_;
        }
      }
      __syncthreads();
    }

    float tk0[4], tk1[4];
#pragma unroll
    for (int r = 0; r < 4; ++r) {
      int row = quad * 4 + r;
      tk0[r] = tok_lds[row * 2];
      tk1[r] = tok_lds[row * 2 + 1];
    }
    f4 acc[4];
#pragma unroll
    for (int g = 0; g < 4; ++g) {
#pragma unroll
      for (int r = 0; r < 4; ++r)
        acc[g][r] = db[g] + tk0[r] * D0[g] + tk1[r] * D1[g];
    }
#pragma unroll
    for (int s8 = 0; s8 < 8; ++s8) {
#pragma unroll
      for (int g = 0; g < 4; ++g)
        acc[g] = __builtin_amdgcn_mfma_f32_16x16x32_f16(ha[s8], W[g][s8], acc[g], 0, 0, 0);
    }

    _Float16* hw = hbuf + parW * 65536 + hrow_wr;
#pragma unroll
    for (int r = 0; r < 4; ++r) {
      float iv = sigf(acc[0][r]);
      float fv = sigf(acc[1][r]);
      float gv = tanh_f(acc[2][r]);
      float ov = sigf(acc[3][r]);
      float cc = fv * c_frag[r] + iv * gv;
      c_frag[r] = cc;
      hw[r * 256] = (_Float16)(ov * tanh_f(cc));
    }

    __syncthreads();
    if (tid == 0) {
      __hip_atomic_fetch_add(ctr + tile, 1, __ATOMIC_RELEASE, __HIP_MEMORY_SCOPE_AGENT);
      while (__hip_atomic_load(ctr + tile, __ATOMIC_ACQUIRE, __HIP_MEMORY_SCOPE_AGENT)
             < 2 * (t + 1)) { }
    }
    __syncthreads();
  }

  // final pred_34 from h after last decoder step (parity (1024+35)&1 = 1)
  {
    const _Float16* hb = hbuf + 1 * 65536 + hrow_rd;
    h8 ha[8];
#pragma unroll
    for (int s8 = 0; s8 < 8; ++s8)
      ha[s8] = *reinterpret_cast<const h8*>(hb + s8 * 32);
    f4 pf; pf[0] = bm; pf[1] = bm; pf[2] = bm; pf[3] = bm;
#pragma unroll
    for (int s8 = 0; s8 < 8; ++s8) {
      h8 wb = *reinterpret_cast<const h8*>(&wm_lds[(s8 * 64 + lane) * 8]);
      pf = __builtin_amdgcn_mfma_f32_16x16x32_f16(ha[s8], wb, pf, 0, 0, 0);
    }
    if (half_id == 0 && wave == 0 && n < 2) {
#pragma unroll
      for (int r = 0; r < 4; ++r) {
        int row = quad * 4 + r;
        out[((b0 + row) * 35 + 34) * 2 + n] = pf[r] * sw + sb_;
      }
    }
  }
}

extern "C" void kernel_launch(void* const* d_in, const int* in_sizes, int n_in,
                              void* d_out, int out_size, void* d_ws, size_t ws_size,
                              hipStream_t stream) {
  const float* pulse    = (const float*)d_in[0];
  const float* bn_gamma = (const float*)d_in[1];
  const float* bn_beta  = (const float*)d_in[2];
  const float* bn_mean  = (const float*)d_in[3];
  const float* bn_var   = (const float*)d_in[4];
  const float* W_pulse  = (const float*)d_in[5];
  const float* b_pulse  = (const float*)d_in[6];
  const float* lstm_k   = (const float*)d_in[7];
  const float* lstm_rk  = (const float*)d_in[8];
  const float* lstm_b   = (const float*)d_in[9];
  const float* embed    = (const float*)d_in[10];
  const float* W_eis    = (const float*)d_in[11];
  const float* b_eis    = (const float*)d_in[12];
  const float* W_mlp    = (const float*)d_in[13];
  const float* b_mlp    = (const float*)d_in[14];
  const float* scale_w  = (const float*)d_in[15];
  const float* scale_b  = (const float*)d_in[16];

  char* ws = (char*)d_ws;
  int*      ctr   = (int*)(ws + WS_CTR);
  _Float16* hbuf  = (_Float16*)(ws + WS_HBUF);
  _Float16* rkT   = (_Float16*)(ws + WS_RKT);
  _Float16* WeffT = (_Float16*)(ws + WS_WEFF);
  _Float16* WmlpT = (_Float16*)(ws + WS_WMLP);
  float*    Deff  = (float*)(ws + WS_DEFF);
  float*    zbias = (float*)(ws + WS_ZB);
  float*    dbias = (float*)(ws + WS_DB);

  // zero counters + h double-buffer (262400 bytes = 65600 words)
  zero_ws_k<<<257, 256, 0, stream>>>((uint32_t*)d_ws, 65600);
  precompute_k<<<1024, 256, 0, stream>>>(bn_gamma, bn_beta, bn_mean, bn_var,
                                         W_pulse, b_pulse, lstm_k, lstm_rk, lstm_b,
                                         W_eis, b_eis, W_mlp,
                                         rkT, WeffT, WmlpT, Deff, zbias, dbias);
  lstm_main_k<<<32, 512, 0, stream>>>(pulse, embed, b_mlp, scale_w, scale_b,
                                      rkT, WeffT, WmlpT, Deff, zbias, dbias,
                                      hbuf, ctr, (float*)d_out);
}